// Round 3
// baseline (44694.058 us; speedup 1.0000x reference)
//
#include <hip/hip_runtime.h>

// FPS: x (B=64, N=65536, 3) f32 -> out (B, M=2048, 3) f32 gathered points.
// Index selection must match the harness reference bitwise.
// Round-3 theory: reference (XLA CPU, SLP-vectorized pair + scalar tail with
// FMA contraction) computes
//   d = fma(dz,dz, round(round(dx*dx) + round(dy*dy)))
// min via fminf, argmax tie-break = smallest index (first occurrence).
// History: all-rounded -> absmax 4.02; full-fma-chain -> absmax 1.83.

#define FPS_B 64
#define FPS_N 65536
#define FPS_M 2048
#define FPS_T 1024
#define FPS_PPT (FPS_N / FPS_T)   // 64 points per thread
#define FPS_WAVES (FPS_T / 64)    // 16 waves per block

__global__ __launch_bounds__(FPS_T) void fps_kernel(const float* __restrict__ x,
                                                    float* __restrict__ out) {
    const int b = blockIdx.x;
    const float* xb = x + (size_t)b * FPS_N * 3;
    float* ob = out + (size_t)b * FPS_M * 3;

    __shared__ float s_val[FPS_WAVES];
    __shared__ int   s_idx[FPS_WAVES];
    __shared__ float s_p[3];

    const int t = threadIdx.x;
    const int wave = t >> 6;
    const int lane = t & 63;

    // per-thread min-distance state, register-resident (static indexing)
    float mind[FPS_PPT];
#pragma unroll
    for (int k = 0; k < FPS_PPT; ++k) mind[k] = INFINITY;

    // idxs[0] = 0 -> out[0] = x[0]; seed the broadcast point
    if (t == 0) {
        float qx = xb[0], qy = xb[1], qz = xb[2];
        ob[0] = qx; ob[1] = qy; ob[2] = qz;
        s_p[0] = qx; s_p[1] = qy; s_p[2] = qz;
    }
    __syncthreads();

    float px = s_p[0], py = s_p[1], pz = s_p[2];

    for (int s = 1; s < FPS_M; ++s) {
        float best = -INFINITY;
        int besti = 0;
        // Update min_d with distance to current point p; track local argmax.
        // Per-thread traversal is ascending global index (k*T + t); strict '>'
        // keeps the first (smallest-index) max within a thread.
#pragma unroll
        for (int k = 0; k < FPS_PPT; ++k) {
            const int i = k * FPS_T + t;
            const float xx = xb[3 * i + 0];
            const float yy = xb[3 * i + 1];
            const float zz = xb[3 * i + 2];
            const float dx = __fsub_rn(xx, px);
            const float dy = __fsub_rn(yy, py);
            const float dz = __fsub_rn(zz, pz);
            // SLP pair + contracted tail: fma(dz,dz, (dx^2 + dy^2))
            const float sxy = __fadd_rn(__fmul_rn(dx, dx), __fmul_rn(dy, dy));
            const float d = __builtin_fmaf(dz, dz, sxy);
            const float md = fminf(mind[k], d);
            mind[k] = md;
            if (md > best) { best = md; besti = i; }
        }

        // wave-level (64-lane) argmax reduce with smallest-index tie-break
#pragma unroll
        for (int m = 32; m >= 1; m >>= 1) {
            const float ov = __shfl_xor(best, m);
            const int   oi = __shfl_xor(besti, m);
            if (ov > best || (ov == best && oi < besti)) { best = ov; besti = oi; }
        }
        if (lane == 0) { s_val[wave] = best; s_idx[wave] = besti; }
        __syncthreads();

        // block-level combine + output write by thread 0
        if (t == 0) {
            float bv = s_val[0];
            int   bi = s_idx[0];
#pragma unroll
            for (int w = 1; w < FPS_WAVES; ++w) {
                const float ov = s_val[w];
                const int   oi = s_idx[w];
                if (ov > bv || (ov == bv && oi < bi)) { bv = ov; bi = oi; }
            }
            const float qx = xb[3 * bi + 0];
            const float qy = xb[3 * bi + 1];
            const float qz = xb[3 * bi + 2];
            ob[3 * s + 0] = qx; ob[3 * s + 1] = qy; ob[3 * s + 2] = qz;
            s_p[0] = qx; s_p[1] = qy; s_p[2] = qz;
        }
        __syncthreads();
        px = s_p[0]; py = s_p[1]; pz = s_p[2];
    }
}

extern "C" void kernel_launch(void* const* d_in, const int* in_sizes, int n_in,
                              void* d_out, int out_size, void* d_ws, size_t ws_size,
                              hipStream_t stream) {
    const float* x = (const float*)d_in[0];
    float* out = (float*)d_out;
    (void)in_sizes; (void)n_in; (void)out_size; (void)d_ws; (void)ws_size;
    fps_kernel<<<FPS_B, FPS_T, 0, stream>>>(x, out);
}

// Round 4
// 9342.425 us; speedup vs baseline: 4.7840x; 4.7840x over previous
//
#include <hip/hip_runtime.h>

// FPS: x (B=64, N=65536, 3) f32 -> out (B, M=2048, 3) f32 gathered points.
// Verified fp semantics (round 3, absmax=0):
//   d = fma(dz,dz, round(dx*dx) + round(dy*dy)), min via fminf,
//   argmax tie-break = smallest global index.
// Round-4 structure: 4 blocks per batch, coords register-resident,
// cross-block lockstep via seq-stamped packed u64 agent-scope atomics
// (depth-2 ring slot => lossless bounded lockstep, no overwrite race).

#define FPS_B 64
#define FPS_N 65536
#define FPS_M 2048
#define FPS_T 1024
#define FPS_Q 4                    // blocks per batch
#define FPS_GT (FPS_T * FPS_Q)     // 4096 threads per batch
#define FPS_PPT (FPS_N / FPS_GT)   // 16 points per thread
#define FPS_WAVES (FPS_T / 64)     // 16 waves per block

// workspace: per batch, 4 blocks x 2 ring slots, each padded to 64B
// total = 64 * 8 * 64B = 32 KiB
#define SLOT_U64 8                 // 64B / 8
#define BATCH_U64 (FPS_Q * 2 * SLOT_U64)

__global__ __launch_bounds__(FPS_T, 4)
void fps_kernel(const float* __restrict__ x, float* __restrict__ out,
                unsigned long long* __restrict__ cand) {
    const int bid = blockIdx.x;
    const int b = bid >> 2;
    const int q = bid & 3;
    const float* xb = x + (size_t)b * FPS_N * 3;
    float* ob = out + (size_t)b * FPS_M * 3;
    unsigned long long* cb = cand + (size_t)b * BATCH_U64;

    __shared__ float s_val[FPS_WAVES];
    __shared__ int   s_idx[FPS_WAVES];
    __shared__ float s_p[3];

    const int t = threadIdx.x;
    const int wave = t >> 6;
    const int lane = t & 63;
    const int g = q * FPS_T + t;   // 0..4095 within batch

    // one-time coordinate load; points i = k*4096 + g (ascending in k)
    float cx[FPS_PPT], cy[FPS_PPT], cz[FPS_PPT], mind[FPS_PPT];
#pragma unroll
    for (int k = 0; k < FPS_PPT; ++k) {
        const int i = k * FPS_GT + g;
        cx[k] = xb[3 * i + 0];
        cy[k] = xb[3 * i + 1];
        cz[k] = xb[3 * i + 2];
        mind[k] = INFINITY;
    }

    float px = xb[0], py = xb[1], pz = xb[2];
    if (q == 0 && t == 0) { ob[0] = px; ob[1] = py; ob[2] = pz; }

    long long poll_budget = 1LL << 19;   // fail-safe: degrade, don't hang

    for (int s = 1; s < FPS_M; ++s) {
        float best = -INFINITY;
        int besti = 0;
#pragma unroll
        for (int k = 0; k < FPS_PPT; ++k) {
            const float dx = __fsub_rn(cx[k], px);
            const float dy = __fsub_rn(cy[k], py);
            const float dz = __fsub_rn(cz[k], pz);
            const float sxy = __fadd_rn(__fmul_rn(dx, dx), __fmul_rn(dy, dy));
            const float d = __builtin_fmaf(dz, dz, sxy);
            const float md = fminf(mind[k], d);
            mind[k] = md;
            if (md > best) { best = md; besti = k * FPS_GT + g; }
        }

        // wave argmax (64 lanes), smallest-index tie-break
#pragma unroll
        for (int m = 32; m >= 1; m >>= 1) {
            const float ov = __shfl_xor(best, m);
            const int   oi = __shfl_xor(besti, m);
            if (ov > best || (ov == best && oi < besti)) { best = ov; besti = oi; }
        }
        if (lane == 0) { s_val[wave] = best; s_idx[wave] = besti; }
        __syncthreads();

        if (t == 0) {
            float bv = s_val[0];
            int   bi = s_idx[0];
#pragma unroll
            for (int w = 1; w < FPS_WAVES; ++w) {
                const float ov = s_val[w];
                const int   oi = s_idx[w];
                if (ov > bv || (ov == bv && oi < bi)) { bv = ov; bi = oi; }
            }
            // pack: [63:32]=val bits (val>=0 => monotone), [26:11]=~idx
            // (smaller idx wins ties under max), [10:0]=seq
            const unsigned long long pk =
                ((unsigned long long)__float_as_uint(bv) << 32) |
                ((unsigned long long)((~(unsigned)bi) & 0xFFFFu) << 11) |
                (unsigned long long)s;
            const int ring = s & 1;
            __hip_atomic_store(&cb[(q * 2 + ring) * SLOT_U64], pk,
                               __ATOMIC_RELAXED, __HIP_MEMORY_SCOPE_AGENT);

            unsigned long long g0 = 0, g1 = 0, g2 = 0, g3 = 0;
            unsigned mask = 0xFu & ~(1u << q);
            if (q == 0) g0 = pk; else if (q == 1) g1 = pk;
            else if (q == 2) g2 = pk; else g3 = pk;
            const unsigned long long want = (unsigned long long)s;
            while (mask && poll_budget > 0) {
                if (mask & 1u) {
                    unsigned long long v = __hip_atomic_load(&cb[(0 * 2 + ring) * SLOT_U64], __ATOMIC_RELAXED, __HIP_MEMORY_SCOPE_AGENT);
                    if ((v & 0x7FFull) == want) { g0 = v; mask &= ~1u; }
                }
                if (mask & 2u) {
                    unsigned long long v = __hip_atomic_load(&cb[(1 * 2 + ring) * SLOT_U64], __ATOMIC_RELAXED, __HIP_MEMORY_SCOPE_AGENT);
                    if ((v & 0x7FFull) == want) { g1 = v; mask &= ~2u; }
                }
                if (mask & 4u) {
                    unsigned long long v = __hip_atomic_load(&cb[(2 * 2 + ring) * SLOT_U64], __ATOMIC_RELAXED, __HIP_MEMORY_SCOPE_AGENT);
                    if ((v & 0x7FFull) == want) { g2 = v; mask &= ~4u; }
                }
                if (mask & 8u) {
                    unsigned long long v = __hip_atomic_load(&cb[(3 * 2 + ring) * SLOT_U64], __ATOMIC_RELAXED, __HIP_MEMORY_SCOPE_AGENT);
                    if ((v & 0x7FFull) == want) { g3 = v; mask &= ~8u; }
                }
                --poll_budget;
            }
            const unsigned long long w01 = g0 > g1 ? g0 : g1;
            const unsigned long long w23 = g2 > g3 ? g2 : g3;
            const unsigned long long w = w01 > w23 ? w01 : w23;
            const int widx = (int)((~(unsigned)(w >> 11)) & 0xFFFFu);
            const float qx = xb[3 * widx + 0];
            const float qy = xb[3 * widx + 1];
            const float qz = xb[3 * widx + 2];
            if (q == 0) { ob[3 * s + 0] = qx; ob[3 * s + 1] = qy; ob[3 * s + 2] = qz; }
            s_p[0] = qx; s_p[1] = qy; s_p[2] = qz;
        }
        __syncthreads();
        px = s_p[0]; py = s_p[1]; pz = s_p[2];
    }
}

extern "C" void kernel_launch(void* const* d_in, const int* in_sizes, int n_in,
                              void* d_out, int out_size, void* d_ws, size_t ws_size,
                              hipStream_t stream) {
    const float* x = (const float*)d_in[0];
    float* out = (float*)d_out;
    unsigned long long* cand = (unsigned long long*)d_ws;
    (void)in_sizes; (void)n_in; (void)out_size; (void)ws_size;
    // zero the sync workspace each launch: stale seq values from a previous
    // replay can never match (all seq written this launch are >= 1)
    hipMemsetAsync(d_ws, 0, FPS_B * BATCH_U64 * sizeof(unsigned long long), stream);
    fps_kernel<<<FPS_B * FPS_Q, FPS_T, 0, stream>>>(x, out, cand);
}